// Round 6
// baseline (436.315 us; speedup 1.0000x reference)
//
#include <hip/hip_runtime.h>

// FastMultiTaskGP: FFT(65536) of 136 upper-tri k1 rows + 16 y rows (ortho),
// per-frequency 16x16 Schur-complement inversion (Hermitian), logdet + quad,
// write A.re / A.im (134 MB) + 2 scalars.
//
// Conjugate symmetry: real inputs => A(N-f)=conj(A(f)); invert f=0..32768,
// mirror-write the rest, weight logdet/quad by 2 for 0<f<32768.
// Inversion: 4 lanes per frequency (lane owns rows 4g..4g+3), 64 freqs per
// 256-thread block. Tm exchange via DPP quad_perm (pure VALU). lam/yt read
// DIRECTLY from global (L2/L3-resident, quad-uniform addrs, 128B/instr) --
// no LDS staging. LDS only holds the 33KB store plane (4 row-chunks).

#define TT 16
#define NF 65536
#define NPAIR 136
#define NROWS 152
#define NHALF 32768

static const size_t AIMAG  = 16777216;   // 16*16*65536
static const size_t OUT_LD = 33554432;
static const size_t OUT_QD = 33554433;

typedef float2 c32;

__device__ __forceinline__ c32 cmul(c32 a, c32 b) { return make_float2(a.x*b.x - a.y*b.y, a.x*b.y + a.y*b.x); }
__device__ __forceinline__ c32 cadd(c32 a, c32 b) { return make_float2(a.x + b.x, a.y + b.y); }
__device__ __forceinline__ c32 csub(c32 a, c32 b) { return make_float2(a.x - b.x, a.y - b.y); }

// DPP helpers (ctrl must be a literal/ICE at each use site)
#define DPPF(x, ctrl) __int_as_float(__builtin_amdgcn_update_dpp( \
    __float_as_int(x), __float_as_int(x), (ctrl), 0xF, 0xF, false))
// quad xor1 = 0xB1 ; quad xor2 = 0x4E ; bcast lane q = 0x55*q

__constant__ c32 W16[16] = {
  { 1.0f, 0.0f}, { 0.92387953f,-0.38268343f}, { 0.70710678f,-0.70710678f}, { 0.38268343f,-0.92387953f},
  { 0.0f,-1.0f}, {-0.38268343f,-0.92387953f}, {-0.70710678f,-0.70710678f}, {-0.92387953f,-0.38268343f},
  {-1.0f, 0.0f}, {-0.92387953f, 0.38268343f}, {-0.70710678f, 0.70710678f}, {-0.38268343f, 0.92387953f},
  { 0.0f, 1.0f}, { 0.38268343f, 0.92387953f}, { 0.70710678f, 0.70710678f}, { 0.92387953f, 0.38268343f}
};

__device__ __forceinline__ void dft4(c32 a0, c32 a1, c32 a2, c32 a3,
                                     c32& c0, c32& c1, c32& c2, c32& c3) {
  c32 s0 = cadd(a0, a2), s1 = csub(a0, a2);
  c32 s2 = cadd(a1, a3), s3 = csub(a1, a3);
  c0 = cadd(s0, s2);
  c2 = csub(s0, s2);
  c1 = make_float2(s1.x + s3.y, s1.y - s3.x);
  c3 = make_float2(s1.x - s3.y, s1.y + s3.x);
}

__device__ __forceinline__ void dft16(c32 v[16]) {
  c32 t[16];
  #pragma unroll
  for (int p = 0; p < 4; ++p) {
    c32 c0, c1, c2, c3;
    dft4(v[p], v[p+4], v[p+8], v[p+12], c0, c1, c2, c3);
    t[4*p+0] = c0;
    t[4*p+1] = cmul(c1, W16[p]);
    t[4*p+2] = cmul(c2, W16[(2*p) & 15]);
    t[4*p+3] = cmul(c3, W16[(3*p) & 15]);
  }
  #pragma unroll
  for (int q = 0; q < 4; ++q) {
    c32 c0, c1, c2, c3;
    dft4(t[q], t[q+4], t[q+8], t[q+12], c0, c1, c2, c3);
    v[q+0]  = c0;
    v[q+4]  = c1;
    v[q+8]  = c2;
    v[q+12] = c3;
  }
}

__global__ __launch_bounds__(256) void fft_pass1(const float* __restrict__ k1,
                                                 const float* __restrict__ y,
                                                 c32* __restrict__ out) {
  const int row = blockIdx.y;
  const float* src;
  float scale = 1.0f;
  if (row < NPAIR) {
    int i = 0, rem = row;
    while (rem >= TT - i) { rem -= TT - i; ++i; }
    int j = i + rem;
    src = k1 + (size_t)(i * TT + j) * NF;
  } else {
    src = y + (size_t)(row - NPAIR) * NF;
    scale = 1.0f / 256.0f;   // ortho norm
  }
  const int p = blockIdx.x * 256 + threadIdx.x;   // [0,4096)
  c32 v[16];
  #pragma unroll
  for (int i = 0; i < 16; ++i) v[i] = make_float2(src[p + 4096*i] * scale, 0.0f);
  dft16(v);
  float sa, ca;
  __sincosf(-6.2831853071795865f * (float)p / 65536.0f, &sa, &ca);
  c32 w1 = make_float2(ca, sa);
  c32 wj = w1;
  c32* dst = out + (size_t)row * NF + 16 * p;
  dst[0] = v[0];
  #pragma unroll
  for (int j = 1; j < 16; ++j) { dst[j] = cmul(v[j], wj); wj = cmul(wj, w1); }
}

// Stockham radix-16 pass: length NN, stride S. TRIM: last pass stores j<=8
// (covers all f < 36864 that invert reads).
template<int NN, int S, bool TRIM>
__global__ __launch_bounds__(256) void fft_pass(const c32* __restrict__ in,
                                                c32* __restrict__ out) {
  const int w = blockIdx.x * 256 + threadIdx.x;   // [0,4096)
  const int q = w & (S - 1);
  const int p = w / S;
  const size_t rbase = (size_t)blockIdx.y * NF;
  c32 v[16];
  #pragma unroll
  for (int i = 0; i < 16; ++i) v[i] = in[rbase + w + 4096*i];
  dft16(v);
  if constexpr (NN > 16) {
    float sa, ca;
    __sincosf(-6.2831853071795865f * (float)p / (float)NN, &sa, &ca);
    c32 w1 = make_float2(ca, sa);
    c32 wj = w1;
    #pragma unroll
    for (int j = 1; j < 16; ++j) { v[j] = cmul(v[j], wj); wj = cmul(wj, w1); }
  }
  c32* dst = out + rbase + q + (size_t)S * 16 * p;
  #pragma unroll
  for (int j = 0; j < 16; ++j) {
    if (!TRIM || j <= 8) dst[(size_t)S * j] = v[j];
  }
}

__global__ void init_out(float* __restrict__ out) {
  if (threadIdx.x == 0 && blockIdx.x == 0) {
    out[OUT_LD] = 0.0f;
    out[OUT_QD] = 0.0f;
  }
}

// ---- Schur step L (compile-time), 4 lanes/freq, lane owns rows 4g..4g+3 ----
// lamf: spec + f (global, L2-hot); entry e at lamf[e * NF]. All e are ICEs.
#define UPDATE_J(J)                                                          \
  if constexpr ((J) < L) {                                                   \
    float tjr = DPPF(tr[(J)&3], 0x55*((J)>>2));                              \
    float tji = DPPF(ti[(J)&3], 0x55*((J)>>2));                              \
    _Pragma("unroll")                                                        \
    for (int m = 0; m < 4; ++m) {                                            \
      Ar[m][(J)] = mf[m]*Ar[m][(J)] + cr[m]*tjr + ci[m]*tji;                 \
      Ai[m][(J)] = mf[m]*Ai[m][(J)] + ci[m]*tjr - cr[m]*tji;                 \
    }                                                                        \
  }

template<int L>
__device__ __forceinline__ void schur_step(const c32* __restrict__ lamf,
                                           float (&Ar)[4][16], float (&Ai)[4][16],
                                           const int (&row)[4], const int (&ro)[4],
                                           float& ld) {
  float tr[4] = {0.f,0.f,0.f,0.f}, ti[4] = {0.f,0.f,0.f,0.f};
  #pragma unroll
  for (int k = 0; k < L; ++k) {
    c32 B = lamf[(size_t)((((k*(31-k))>>1) + L)) * NF];   // quad-uniform addr
    #pragma unroll
    for (int m = 0; m < 4; ++m) {
      tr[m] += Ar[m][k]*B.x - Ai[m][k]*B.y;
      ti[m] += Ar[m][k]*B.y + Ai[m][k]*B.x;
    }
  }
  // partial M over own rows (rows >= L have Tm = 0; garbage B harmless/finite)
  float mr = 0.f, mi = 0.f;
  #pragma unroll
  for (int m = 0; m < 4; ++m) {
    c32 Bo = lamf[(size_t)(ro[m] + L) * NF];
    mr += Bo.x*tr[m] + Bo.y*ti[m];
    mi += Bo.x*ti[m] - Bo.y*tr[m];
  }
  // quad xor-reduce -> all 4 lanes hold full M
  mr += DPPF(mr, 0xB1); mi += DPPF(mi, 0xB1);
  mr += DPPF(mr, 0x4E); mi += DPPF(mi, 0x4E);

  c32 ll = lamf[(size_t)((((L*(31-L))>>1) + L)) * NF];
  float Sr = ll.x - mr, Si = ll.y - mi;
  float s2 = Sr*Sr + Si*Si;
  ld += 0.5f * __logf(s2);
  float is2 = 1.0f / s2;
  float vr = Sr * is2, vi = -Si * is2;         // Sinv

  float pr[4], pi[4], cr[4], ci[4], mf[4];
  #pragma unroll
  for (int m = 0; m < 4; ++m) {
    pr[m] = tr[m]*vr - ti[m]*vi;               // P (0 for rows > L)
    pi[m] = tr[m]*vi + ti[m]*vr;
    bool diag = (row[m] == L);
    cr[m] = diag ? -vr : pr[m];
    ci[m] = diag ?  vi : pi[m];
    mf[m] = diag ? 0.0f : 1.0f;
  }
  UPDATE_J(0)  UPDATE_J(1)  UPDATE_J(2)  UPDATE_J(3)
  UPDATE_J(4)  UPDATE_J(5)  UPDATE_J(6)  UPDATE_J(7)
  UPDATE_J(8)  UPDATE_J(9)  UPDATE_J(10) UPDATE_J(11)
  UPDATE_J(12) UPDATE_J(13) UPDATE_J(14) UPDATE_J(15)
  #pragma unroll
  for (int m = 0; m < 4; ++m) {
    bool diag = (row[m] == L);
    Ar[m][L] = diag ? vr : -pr[m];
    Ai[m][L] = diag ? vi : -pi[m];
  }
}

__global__ __launch_bounds__(256) void invert_write(const c32* __restrict__ spec,
                                                    float* __restrict__ out) {
  __shared__ c32 plane[64][65];      // [freq][chunk-local rr]; 33.3 KB
  __shared__ float redl[4], redq[4];

  const int t  = threadIdx.x;
  const int fi = t >> 2;            // freq within block [0,64)
  const int g  = t & 3;             // quad lane = row group
  const int f0 = blockIdx.x << 6;
  const int f  = f0 + fi;

  int row[4], ro[4];
  #pragma unroll
  for (int m = 0; m < 4; ++m) {
    row[m] = 4*g + m;
    ro[m]  = (row[m] * (31 - row[m])) >> 1;
  }

  const c32* lamf = spec + f;
  const c32* ytf  = spec + (size_t)NPAIR * NF + f;

  float Ar[4][16], Ai[4][16];
  #pragma unroll
  for (int m = 0; m < 4; ++m)
    #pragma unroll
    for (int j = 0; j < 16; ++j) { Ar[m][j] = 0.0f; Ai[m][j] = 0.0f; }

  c32 l00 = lamf[0];
  float m00 = l00.x*l00.x + l00.y*l00.y;
  float im00 = 1.0f / m00;
  float ld = 0.5f * __logf(m00);
  if (row[0] == 0) {                 // only lane g==0 owns row 0
    Ar[0][0] =  l00.x * im00;
    Ai[0][0] = -l00.y * im00;
  }

  schur_step< 1>(lamf, Ar, Ai, row, ro, ld);
  schur_step< 2>(lamf, Ar, Ai, row, ro, ld);
  schur_step< 3>(lamf, Ar, Ai, row, ro, ld);
  schur_step< 4>(lamf, Ar, Ai, row, ro, ld);
  schur_step< 5>(lamf, Ar, Ai, row, ro, ld);
  schur_step< 6>(lamf, Ar, Ai, row, ro, ld);
  schur_step< 7>(lamf, Ar, Ai, row, ro, ld);
  schur_step< 8>(lamf, Ar, Ai, row, ro, ld);
  schur_step< 9>(lamf, Ar, Ai, row, ro, ld);
  schur_step<10>(lamf, Ar, Ai, row, ro, ld);
  schur_step<11>(lamf, Ar, Ai, row, ro, ld);
  schur_step<12>(lamf, Ar, Ai, row, ro, ld);
  schur_step<13>(lamf, Ar, Ai, row, ro, ld);
  schur_step<14>(lamf, Ar, Ai, row, ro, ld);
  schur_step<15>(lamf, Ar, Ai, row, ro, ld);

  // quad: qd partial over own rows, then quad-reduce
  float qd = 0.0f;
  #pragma unroll
  for (int m = 0; m < 4; ++m) {
    float sr = 0.f, si = 0.f;
    #pragma unroll
    for (int j = 0; j < 16; ++j) {
      c32 yj = ytf[(size_t)j * NF];
      sr += Ar[m][j]*yj.x - Ai[m][j]*yj.y;
      si += Ar[m][j]*yj.y + Ai[m][j]*yj.x;
    }
    c32 yo = ytf[(size_t)row[m] * NF];
    qd += yo.x*sr + yo.y*si;
  }
  qd += DPPF(qd, 0xB1);
  qd += DPPF(qd, 0x4E);

  float w  = (f == 0 || f == NHALF) ? 1.0f : (f < NHALF ? 2.0f : 0.0f);
  float lw = (g == 0) ? ld * w : 0.0f;
  float qw = (g == 0) ? qd * w : 0.0f;

  #pragma unroll
  for (int d = 1; d < 64; d <<= 1) {
    lw += __shfl_xor(lw, d, 64);
    qw += __shfl_xor(qw, d, 64);
  }
  if ((t & 63) == 0) { redl[t >> 6] = lw; redq[t >> 6] = qw; }
  __syncthreads();
  if (t == 0) {
    atomicAdd(out + OUT_LD, redl[0] + redl[1] + redl[2] + redl[3]);
    atomicAdd(out + OUT_QD, redq[0] + redq[1] + redq[2] + redq[3]);
  }

  // ---- store via LDS plane, 4 chunks (chunk c = each lane's m==c row) ----
  // chunk c holds rows 4g'+c; chunk-local lrr = g'*16 + j.
  const int fl  = t & 63;
  const int wid = t >> 6;
  const int fg  = f0 + fl;
  const bool dok = (fg <= NHALF);
  const bool mok = (fg > 0 && fg < NHALF);
  const size_t fD = (size_t)fg;
  const size_t fM = (size_t)(NF - fg);

  #pragma unroll
  for (int c = 0; c < 4; ++c) {
    #pragma unroll
    for (int j = 0; j < 16; ++j)
      plane[fi][g * 16 + j] = make_float2(Ar[c][j], Ai[c][j]);
    __syncthreads();
    #pragma unroll
    for (int it = 0; it < 16; ++it) {
      int lrr = wid + 4 * it;
      c32 v = plane[fl][lrr];
      int rr = ((lrr >> 4) * 4 + c) * 16 + (lrr & 15);
      size_t o = (size_t)rr * NF;
      if (dok) { out[o + fD] = v.x;  out[AIMAG + o + fD] =  v.y; }
      if (mok) { out[o + fM] = v.x;  out[AIMAG + o + fM] = -v.y; }
    }
    __syncthreads();
  }
}

extern "C" void kernel_launch(void* const* d_in, const int* in_sizes, int n_in,
                              void* d_out, int out_size, void* d_ws, size_t ws_size,
                              hipStream_t stream) {
  const float* k1 = (const float*)d_in[0];
  const float* y  = (const float*)d_in[1];
  float* out = (float*)d_out;
  c32* scratch = (c32*)d_out;   // 79.7 MB < 134 MB out buffer, overwritten later
  c32* spec    = (c32*)d_ws;    // 76 MiB workspace

  dim3 grid(16, NROWS);
  dim3 blk(256);

  fft_pass1                <<<grid, blk, 0, stream>>>(k1, y, scratch);
  fft_pass<4096, 16, false><<<grid, blk, 0, stream>>>(scratch, spec);
  fft_pass<256, 256, false><<<grid, blk, 0, stream>>>(spec, scratch);
  fft_pass<16, 4096, true> <<<grid, blk, 0, stream>>>(scratch, spec);

  init_out<<<1, 64, 0, stream>>>(out);
  invert_write<<<513, blk, 0, stream>>>(spec, out);   // f = 0..32768 (+tail)
}

// Round 7
// 225.642 us; speedup vs baseline: 1.9337x; 1.9337x over previous
//
#include <hip/hip_runtime.h>

// FastMultiTaskGP: FFT(65536) of 136 upper-tri k1 rows + 16 y rows (ortho),
// per-frequency 16x16 Schur-complement inversion (Hermitian), logdet + quad,
// write A.re / A.im (134 MB) + 2 scalars.
//
// Conjugate symmetry: real inputs => A(N-f)=conj(A(f)); invert f=0..32768,
// mirror-write the rest, weight logdet/quad by 2 for 0<f<32768.
// Inversion: 16 lanes per frequency (lane = row), 32 freqs per 512-thread
// block (full 128B-line stores), lam/yts/tmb staged in LDS, l-loop fully
// unrolled, branch-free update, LDS tmb exchange (wave-synchronous).

#define TT 16
#define NF 65536
#define NPAIR 136
#define NROWS 152
#define NHALF 32768
#define FPB 32            // freqs per block

static const size_t AIMAG  = 16777216;   // 16*16*65536
static const size_t OUT_LD = 33554432;
static const size_t OUT_QD = 33554433;

typedef float2 c32;

__device__ __forceinline__ c32 cmul(c32 a, c32 b) { return make_float2(a.x*b.x - a.y*b.y, a.x*b.y + a.y*b.x); }
__device__ __forceinline__ c32 cadd(c32 a, c32 b) { return make_float2(a.x + b.x, a.y + b.y); }
__device__ __forceinline__ c32 csub(c32 a, c32 b) { return make_float2(a.x - b.x, a.y - b.y); }

__constant__ c32 W16[16] = {
  { 1.0f, 0.0f}, { 0.92387953f,-0.38268343f}, { 0.70710678f,-0.70710678f}, { 0.38268343f,-0.92387953f},
  { 0.0f,-1.0f}, {-0.38268343f,-0.92387953f}, {-0.70710678f,-0.70710678f}, {-0.92387953f,-0.38268343f},
  {-1.0f, 0.0f}, {-0.92387953f, 0.38268343f}, {-0.70710678f, 0.70710678f}, {-0.38268343f, 0.92387953f},
  { 0.0f, 1.0f}, { 0.38268343f, 0.92387953f}, { 0.70710678f, 0.70710678f}, { 0.92387953f, 0.38268343f}
};

__device__ __forceinline__ void dft4(c32 a0, c32 a1, c32 a2, c32 a3,
                                     c32& c0, c32& c1, c32& c2, c32& c3) {
  c32 s0 = cadd(a0, a2), s1 = csub(a0, a2);
  c32 s2 = cadd(a1, a3), s3 = csub(a1, a3);
  c0 = cadd(s0, s2);
  c2 = csub(s0, s2);
  c1 = make_float2(s1.x + s3.y, s1.y - s3.x);
  c3 = make_float2(s1.x - s3.y, s1.y + s3.x);
}

__device__ __forceinline__ void dft16(c32 v[16]) {
  c32 t[16];
  #pragma unroll
  for (int p = 0; p < 4; ++p) {
    c32 c0, c1, c2, c3;
    dft4(v[p], v[p+4], v[p+8], v[p+12], c0, c1, c2, c3);
    t[4*p+0] = c0;
    t[4*p+1] = cmul(c1, W16[p]);
    t[4*p+2] = cmul(c2, W16[(2*p) & 15]);
    t[4*p+3] = cmul(c3, W16[(3*p) & 15]);
  }
  #pragma unroll
  for (int q = 0; q < 4; ++q) {
    c32 c0, c1, c2, c3;
    dft4(t[q], t[q+4], t[q+8], t[q+12], c0, c1, c2, c3);
    v[q+0]  = c0;
    v[q+4]  = c1;
    v[q+8]  = c2;
    v[q+12] = c3;
  }
}

__global__ __launch_bounds__(256) void fft_pass1(const float* __restrict__ k1,
                                                 const float* __restrict__ y,
                                                 c32* __restrict__ out) {
  const int row = blockIdx.y;
  const float* src;
  float scale = 1.0f;
  if (row < NPAIR) {
    int i = 0, rem = row;
    while (rem >= TT - i) { rem -= TT - i; ++i; }
    int j = i + rem;
    src = k1 + (size_t)(i * TT + j) * NF;
  } else {
    src = y + (size_t)(row - NPAIR) * NF;
    scale = 1.0f / 256.0f;   // ortho norm
  }
  const int p = blockIdx.x * 256 + threadIdx.x;   // [0,4096)
  c32 v[16];
  #pragma unroll
  for (int i = 0; i < 16; ++i) v[i] = make_float2(src[p + 4096*i] * scale, 0.0f);
  dft16(v);
  float sa, ca;
  __sincosf(-6.2831853071795865f * (float)p / 65536.0f, &sa, &ca);
  c32 w1 = make_float2(ca, sa);
  c32 wj = w1;
  c32* dst = out + (size_t)row * NF + 16 * p;
  dst[0] = v[0];
  #pragma unroll
  for (int j = 1; j < 16; ++j) { dst[j] = cmul(v[j], wj); wj = cmul(wj, w1); }
}

// Stockham radix-16 pass: length NN, stride S. TRIM: last pass stores j<=8
// (covers all f < 36864 that invert reads).
template<int NN, int S, bool TRIM>
__global__ __launch_bounds__(256) void fft_pass(const c32* __restrict__ in,
                                                c32* __restrict__ out) {
  const int w = blockIdx.x * 256 + threadIdx.x;   // [0,4096)
  const int q = w & (S - 1);
  const int p = w / S;
  const size_t rbase = (size_t)blockIdx.y * NF;
  c32 v[16];
  #pragma unroll
  for (int i = 0; i < 16; ++i) v[i] = in[rbase + w + 4096*i];
  dft16(v);
  if constexpr (NN > 16) {
    float sa, ca;
    __sincosf(-6.2831853071795865f * (float)p / (float)NN, &sa, &ca);
    c32 w1 = make_float2(ca, sa);
    c32 wj = w1;
    #pragma unroll
    for (int j = 1; j < 16; ++j) { v[j] = cmul(v[j], wj); wj = cmul(wj, w1); }
  }
  c32* dst = out + rbase + q + (size_t)S * 16 * p;
  #pragma unroll
  for (int j = 0; j < 16; ++j) {
    if (!TRIM || j <= 8) dst[(size_t)S * j] = v[j];
  }
}

__global__ void init_out(float* __restrict__ out) {
  if (threadIdx.x == 0 && blockIdx.x == 0) {
    out[OUT_LD] = 0.0f;
    out[OUT_QD] = 0.0f;
  }
}

__global__ __launch_bounds__(512) void invert_write(const c32* __restrict__ spec,
                                                    float* __restrict__ out) {
  __shared__ union {
    struct {
      c32 lam[FPB][NPAIR + 1];   // [freq][packed entry] 35072 B
      c32 yts[FPB][17];          //  4352 B
      float4 tmb[FPB][17];       //  8704 B
    } rec;                       // 48128 B total
    float plane[FPB][261];       // 33408 B (bank = 5*fl + rr : conflict-free)
  } sh;
  __shared__ float redl[8], redq[8];

  const int t  = threadIdx.x;
  const int fi = t >> 4;            // freq within block [0,32)
  const int r  = t & 15;            // row
  const int f0 = blockIdx.x << 5;
  const int f  = f0 + fi;

  for (int idx = t; idx < NROWS * FPB; idx += 512) {
    int rowi = idx >> 5, ff = idx & 31;
    c32 val = spec[(size_t)rowi * NF + f0 + ff];
    if (rowi < NPAIR) sh.rec.lam[ff][rowi] = val;
    else              sh.rec.yts[ff][rowi - NPAIR] = val;
  }
  __syncthreads();

  const int rowoff = (r * (31 - r)) >> 1;   // pidx(r,l) = rowoff + l

  float Ar[16], Ai[16];
  #pragma unroll
  for (int k = 0; k < 16; ++k) { Ar[k] = 0.0f; Ai[k] = 0.0f; }

  c32 l00 = sh.rec.lam[fi][0];
  float m00 = l00.x*l00.x + l00.y*l00.y;
  float im00 = 1.0f / m00;
  float ld = 0.5f * __logf(m00);            // uniform across group, masked at reduce
  bool r0 = (r == 0);
  Ar[0] = r0 ?  l00.x * im00 : 0.0f;
  Ai[0] = r0 ? -l00.y * im00 : 0.0f;

  #pragma unroll
  for (int l = 1; l < TT; ++l) {
    // Tm[r] = sum_{k<l} A[r][k] * B[k]
    float tr = 0.0f, ti = 0.0f;
    #pragma unroll
    for (int k = 0; k < l; ++k) {
      c32 B = sh.rec.lam[fi][((k * (31 - k)) >> 1) + l];
      tr += Ar[k]*B.x - Ai[k]*B.y;
      ti += Ar[k]*B.y + Ai[k]*B.x;
    }
    c32 Bo = sh.rec.lam[fi][rowoff + l];
    float cbr = Bo.x*tr + Bo.y*ti;
    float cbi = Bo.x*ti - Bo.y*tr;
    sh.rec.tmb[fi][r] = make_float4(tr, ti, cbr, cbi);   // same wave: in-order DS

    float tjr[TT], tji[TT];
    float mr = 0.0f, mi = 0.0f;
    #pragma unroll
    for (int j = 0; j < l; ++j) {
      float4 q = sh.rec.tmb[fi][j];
      tjr[j] = q.x; tji[j] = q.y;
      mr += q.z;    mi += q.w;
    }

    c32 ll = sh.rec.lam[fi][((l * (31 - l)) >> 1) + l];
    float Sr = ll.x - mr, Si = ll.y - mi;
    float s2 = Sr*Sr + Si*Si;
    ld += 0.5f * __logf(s2);
    float is2 = 1.0f / s2;
    float vr =  Sr * is2;                    // Sinv
    float vi = -Si * is2;
    float pr = tr*vr - ti*vi;                // P[r] (0 for r>l)
    float pi = tr*vi + ti*vr;

    bool diag = (r == l);
    float cr = diag ? -vr : pr;
    float ci = diag ?  vi : pi;
    float m  = diag ? 0.0f : 1.0f;

    #pragma unroll
    for (int j = 0; j < l; ++j) {
      Ar[j] = m*Ar[j] + cr*tjr[j] + ci*tji[j];
      Ai[j] = m*Ai[j] + ci*tjr[j] - cr*tji[j];
    }
    Ar[l] = diag ? vr : -pr;
    Ai[l] = diag ? vi : -pi;
  }

  // weights: f=0 / f=32768 once; 0<f<32768 twice; f>32768 excluded
  float w = (f == 0 || f == NHALF) ? 1.0f : (f < NHALF ? 2.0f : 0.0f);

  // quad: Re( conj(yt[r]) * sum_j A[r][j] yt[j] )
  float sr = 0.0f, si = 0.0f;
  #pragma unroll
  for (int j = 0; j < 16; ++j) {
    c32 yj = sh.rec.yts[fi][j];
    sr += Ar[j]*yj.x - Ai[j]*yj.y;
    si += Ar[j]*yj.y + Ai[j]*yj.x;
  }
  c32 yr = sh.rec.yts[fi][r];
  float qd = (yr.x*sr + yr.y*si) * w;
  float lw = r0 ? ld * w : 0.0f;

  #pragma unroll
  for (int d = 1; d < 64; d <<= 1) {
    lw += __shfl_xor(lw, d, 64);
    qw_dummy: ;
    qd += __shfl_xor(qd, d, 64);
  }
  if ((t & 63) == 0) { redl[t >> 6] = lw; redq[t >> 6] = qd; }
  __syncthreads();   // all recursion LDS reads complete before plane reuse
  if (t == 0) {
    float sl = 0.f, sq = 0.f;
    #pragma unroll
    for (int i = 0; i < 8; ++i) { sl += redl[i]; sq += redq[i]; }
    atomicAdd(out + OUT_LD, sl);
    atomicAdd(out + OUT_QD, sq);
  }

  // ---- coalesced store via LDS plane (32 consecutive f = full 128B lines) ----
  const int fl  = t & 31;           // frequency offset within block
  const int cl  = t >> 5;           // row cluster [0,16)
  const int fg  = f0 + fl;
  const bool dok = (fg <= NHALF);
  const bool mok = (fg > 0 && fg < NHALF);
  const size_t fD = (size_t)fg;
  const size_t fM = (size_t)(NF - fg);

  // RE plane (staggered j to avoid 16-stride bank collisions)
  #pragma unroll
  for (int j = 0; j < 16; ++j) {
    int je = (j + r) & 15;
    sh.plane[fi][r * 16 + je] = Ar[je];
  }
  __syncthreads();
  #pragma unroll
  for (int u = 0; u < 16; ++u) {
    int rr = u * 16 + cl;
    float v = sh.plane[fl][rr];
    size_t o = (size_t)rr * NF;
    if (dok) out[o + fD] = v;
    if (mok) out[o + fM] = v;
  }
  __syncthreads();
  // IM plane
  #pragma unroll
  for (int j = 0; j < 16; ++j) {
    int je = (j + r) & 15;
    sh.plane[fi][r * 16 + je] = Ai[je];
  }
  __syncthreads();
  #pragma unroll
  for (int u = 0; u < 16; ++u) {
    int rr = u * 16 + cl;
    float v = sh.plane[fl][rr];
    size_t o = AIMAG + (size_t)rr * NF;
    if (dok) out[o + fD] = v;
    if (mok) out[o + fM] = -v;
  }
}

extern "C" void kernel_launch(void* const* d_in, const int* in_sizes, int n_in,
                              void* d_out, int out_size, void* d_ws, size_t ws_size,
                              hipStream_t stream) {
  const float* k1 = (const float*)d_in[0];
  const float* y  = (const float*)d_in[1];
  float* out = (float*)d_out;
  c32* scratch = (c32*)d_out;   // 79.7 MB < 134 MB out buffer, overwritten later
  c32* spec    = (c32*)d_ws;    // 76 MiB workspace

  dim3 grid(16, NROWS);
  dim3 blk(256);

  fft_pass1                <<<grid, blk, 0, stream>>>(k1, y, scratch);
  fft_pass<4096, 16, false><<<grid, blk, 0, stream>>>(scratch, spec);
  fft_pass<256, 256, false><<<grid, blk, 0, stream>>>(spec, scratch);
  fft_pass<16, 4096, true> <<<grid, blk, 0, stream>>>(scratch, spec);

  init_out<<<1, 64, 0, stream>>>(out);
  invert_write<<<1025, dim3(512), 0, stream>>>(spec, out);  // f = 0..32768 (+tail)
}

// Round 8
// 195.325 us; speedup vs baseline: 2.2338x; 1.1552x over previous
//
#include <hip/hip_runtime.h>
#include <hip/hip_fp16.h>

// FastMultiTaskGP: FFT(65536) of 136 upper-tri k1 rows + 16 y rows (ortho),
// per-frequency 16x16 Schur-complement inversion (Hermitian), logdet + quad,
// write A.re / A.im (134 MB) + 2 scalars.
//
// Conjugate symmetry: real inputs => A(N-f)=conj(A(f)); invert f=0..32768,
// mirror-write the rest, weight logdet/quad by 2 for 0<f<32768.
// Inversion (r4 structure, 256 thr, 16 lanes/freq) with lam stored in LDS as
// fp16 half2 (threshold is 9.6e4 absolute -- fp16's 5e-4 rel error is 4+
// orders inside). LDS/block 24.5->16.7 KB => ~8 blocks/CU (32 waves) for
// latency hiding of the serial per-step chain. XCD-chunked block swizzle so
// adjacent 64B store-halves merge into full 128B lines in one L2.

#define TT 16
#define NF 65536
#define NPAIR 136
#define NROWS 152
#define NHALF 32768

static const size_t AIMAG  = 16777216;   // 16*16*65536
static const size_t OUT_LD = 33554432;
static const size_t OUT_QD = 33554433;

typedef float2 c32;

__device__ __forceinline__ c32 cmul(c32 a, c32 b) { return make_float2(a.x*b.x - a.y*b.y, a.x*b.y + a.y*b.x); }
__device__ __forceinline__ c32 cadd(c32 a, c32 b) { return make_float2(a.x + b.x, a.y + b.y); }
__device__ __forceinline__ c32 csub(c32 a, c32 b) { return make_float2(a.x - b.x, a.y - b.y); }

__constant__ c32 W16[16] = {
  { 1.0f, 0.0f}, { 0.92387953f,-0.38268343f}, { 0.70710678f,-0.70710678f}, { 0.38268343f,-0.92387953f},
  { 0.0f,-1.0f}, {-0.38268343f,-0.92387953f}, {-0.70710678f,-0.70710678f}, {-0.92387953f,-0.38268343f},
  {-1.0f, 0.0f}, {-0.92387953f, 0.38268343f}, {-0.70710678f, 0.70710678f}, {-0.38268343f, 0.92387953f},
  { 0.0f, 1.0f}, { 0.38268343f, 0.92387953f}, { 0.70710678f, 0.70710678f}, { 0.92387953f, 0.38268343f}
};

__device__ __forceinline__ void dft4(c32 a0, c32 a1, c32 a2, c32 a3,
                                     c32& c0, c32& c1, c32& c2, c32& c3) {
  c32 s0 = cadd(a0, a2), s1 = csub(a0, a2);
  c32 s2 = cadd(a1, a3), s3 = csub(a1, a3);
  c0 = cadd(s0, s2);
  c2 = csub(s0, s2);
  c1 = make_float2(s1.x + s3.y, s1.y - s3.x);
  c3 = make_float2(s1.x - s3.y, s1.y + s3.x);
}

__device__ __forceinline__ void dft16(c32 v[16]) {
  c32 t[16];
  #pragma unroll
  for (int p = 0; p < 4; ++p) {
    c32 c0, c1, c2, c3;
    dft4(v[p], v[p+4], v[p+8], v[p+12], c0, c1, c2, c3);
    t[4*p+0] = c0;
    t[4*p+1] = cmul(c1, W16[p]);
    t[4*p+2] = cmul(c2, W16[(2*p) & 15]);
    t[4*p+3] = cmul(c3, W16[(3*p) & 15]);
  }
  #pragma unroll
  for (int q = 0; q < 4; ++q) {
    c32 c0, c1, c2, c3;
    dft4(t[q], t[q+4], t[q+8], t[q+12], c0, c1, c2, c3);
    v[q+0]  = c0;
    v[q+4]  = c1;
    v[q+8]  = c2;
    v[q+12] = c3;
  }
}

__global__ __launch_bounds__(256) void fft_pass1(const float* __restrict__ k1,
                                                 const float* __restrict__ y,
                                                 c32* __restrict__ out) {
  const int row = blockIdx.y;
  const float* src;
  float scale = 1.0f;
  if (row < NPAIR) {
    int i = 0, rem = row;
    while (rem >= TT - i) { rem -= TT - i; ++i; }
    int j = i + rem;
    src = k1 + (size_t)(i * TT + j) * NF;
  } else {
    src = y + (size_t)(row - NPAIR) * NF;
    scale = 1.0f / 256.0f;   // ortho norm
  }
  const int p = blockIdx.x * 256 + threadIdx.x;   // [0,4096)
  c32 v[16];
  #pragma unroll
  for (int i = 0; i < 16; ++i) v[i] = make_float2(src[p + 4096*i] * scale, 0.0f);
  dft16(v);
  float sa, ca;
  __sincosf(-6.2831853071795865f * (float)p / 65536.0f, &sa, &ca);
  c32 w1 = make_float2(ca, sa);
  c32 wj = w1;
  c32* dst = out + (size_t)row * NF + 16 * p;
  dst[0] = v[0];
  #pragma unroll
  for (int j = 1; j < 16; ++j) { dst[j] = cmul(v[j], wj); wj = cmul(wj, w1); }
}

// Stockham radix-16 pass: length NN, stride S. TRIM: last pass stores j<=8
// (covers all f < 36864 that invert reads).
template<int NN, int S, bool TRIM>
__global__ __launch_bounds__(256) void fft_pass(const c32* __restrict__ in,
                                                c32* __restrict__ out) {
  const int w = blockIdx.x * 256 + threadIdx.x;   // [0,4096)
  const int q = w & (S - 1);
  const int p = w / S;
  const size_t rbase = (size_t)blockIdx.y * NF;
  c32 v[16];
  #pragma unroll
  for (int i = 0; i < 16; ++i) v[i] = in[rbase + w + 4096*i];
  dft16(v);
  if constexpr (NN > 16) {
    float sa, ca;
    __sincosf(-6.2831853071795865f * (float)p / (float)NN, &sa, &ca);
    c32 w1 = make_float2(ca, sa);
    c32 wj = w1;
    #pragma unroll
    for (int j = 1; j < 16; ++j) { v[j] = cmul(v[j], wj); wj = cmul(wj, w1); }
  }
  c32* dst = out + rbase + q + (size_t)S * 16 * p;
  #pragma unroll
  for (int j = 0; j < 16; ++j) {
    if (!TRIM || j <= 8) dst[(size_t)S * j] = v[j];
  }
}

__global__ void init_out(float* __restrict__ out) {
  if (threadIdx.x == 0 && blockIdx.x == 0) {
    out[OUT_LD] = 0.0f;
    out[OUT_QD] = 0.0f;
  }
}

// 16 lanes per frequency (lane = row r). l-loop fully unrolled, branch-free
// uniform update, LDS tmb exchange (wave-synchronous). lam in fp16 half2,
// layout [entry][freq] (conflict-free staging writes + broadcast reads).
__global__ __launch_bounds__(256) void invert_write(const c32* __restrict__ spec,
                                                    float* __restrict__ out) {
  __shared__ union {
    struct {
      __half2 lam[NPAIR][16];   // [packed entry][freq]  8704 B
      c32 yts[16][17];          //  2176 B
      float4 tmb[16][17];       //  4352 B
    } rec;                      // 15232 B
    float plane[16][260];       // 16640 B
  } sh;
  __shared__ float redl[4], redq[4];

  // bijective XCD-chunked swizzle: adjacent f-chunks land on the same XCD
  const int nwg  = gridDim.x;           // 2049
  const int orig = blockIdx.x;
  const int xcd  = orig & 7;
  const int pos  = orig >> 3;
  const int qq   = nwg >> 3, rm = nwg & 7;
  const int chunk = (xcd < rm ? xcd * (qq + 1) : rm * (qq + 1) + (xcd - rm) * qq) + pos;

  const int t  = threadIdx.x;
  const int fi = t >> 4;
  const int r  = t & 15;
  const int f0 = chunk << 4;
  const int f  = f0 + fi;

  for (int idx = t; idx < NPAIR * 16; idx += 256) {
    int rowi = idx >> 4, ff = idx & 15;
    c32 val = spec[(size_t)rowi * NF + f0 + ff];
    sh.rec.lam[rowi][ff] = __float22half2_rn(val);
  }
  for (int idx = NPAIR * 16 + t; idx < NROWS * 16; idx += 256) {
    int rowi = idx >> 4, ff = idx & 15;
    sh.rec.yts[ff][rowi - NPAIR] = spec[(size_t)rowi * NF + f0 + ff];
  }
  __syncthreads();

  const int rowoff = (r * (31 - r)) >> 1;   // pidx(r,l) = rowoff + l

  float Ar[16], Ai[16];
  #pragma unroll
  for (int k = 0; k < 16; ++k) { Ar[k] = 0.0f; Ai[k] = 0.0f; }

  c32 l00 = __half22float2(sh.rec.lam[0][fi]);
  float m00 = l00.x*l00.x + l00.y*l00.y;
  float im00 = 1.0f / m00;
  float ld = 0.5f * __logf(m00);            // uniform across group, masked at reduce
  bool r0 = (r == 0);
  Ar[0] = r0 ?  l00.x * im00 : 0.0f;
  Ai[0] = r0 ? -l00.y * im00 : 0.0f;

  #pragma unroll
  for (int l = 1; l < TT; ++l) {
    // Tm[r] = sum_{k<l} A[r][k] * B[k]
    float tr = 0.0f, ti = 0.0f;
    #pragma unroll
    for (int k = 0; k < l; ++k) {
      c32 B = __half22float2(sh.rec.lam[((k * (31 - k)) >> 1) + l][fi]);
      tr += Ar[k]*B.x - Ai[k]*B.y;
      ti += Ar[k]*B.y + Ai[k]*B.x;
    }
    c32 Bo = __half22float2(sh.rec.lam[rowoff + l][fi]);
    float cbr = Bo.x*tr + Bo.y*ti;
    float cbi = Bo.x*ti - Bo.y*tr;
    sh.rec.tmb[fi][r] = make_float4(tr, ti, cbr, cbi);   // same wave: in-order DS

    float tjr[TT], tji[TT];
    float mr = 0.0f, mi = 0.0f;
    #pragma unroll
    for (int j = 0; j < l; ++j) {
      float4 q = sh.rec.tmb[fi][j];
      tjr[j] = q.x; tji[j] = q.y;
      mr += q.z;    mi += q.w;
    }

    c32 ll = __half22float2(sh.rec.lam[((l * (31 - l)) >> 1) + l][fi]);
    float Sr = ll.x - mr, Si = ll.y - mi;
    float s2 = Sr*Sr + Si*Si;
    ld += 0.5f * __logf(s2);
    float is2 = 1.0f / s2;
    float vr =  Sr * is2;                    // Sinv
    float vi = -Si * is2;
    float pr = tr*vr - ti*vi;                // P[r] (0 for r>l)
    float pi = tr*vi + ti*vr;

    bool diag = (r == l);
    float cr = diag ? -vr : pr;
    float ci = diag ?  vi : pi;
    float m  = diag ? 0.0f : 1.0f;

    #pragma unroll
    for (int j = 0; j < l; ++j) {
      Ar[j] = m*Ar[j] + cr*tjr[j] + ci*tji[j];
      Ai[j] = m*Ai[j] + ci*tjr[j] - cr*tji[j];
    }
    Ar[l] = diag ? vr : -pr;
    Ai[l] = diag ? vi : -pi;
  }

  // weights: f=0 / f=32768 once; 0<f<32768 twice; f>32768 excluded
  float w = (f == 0 || f == NHALF) ? 1.0f : (f < NHALF ? 2.0f : 0.0f);

  // quad: Re( conj(yt[r]) * sum_j A[r][j] yt[j] )
  float sr = 0.0f, si = 0.0f;
  #pragma unroll
  for (int j = 0; j < 16; ++j) {
    c32 yj = sh.rec.yts[fi][j];
    sr += Ar[j]*yj.x - Ai[j]*yj.y;
    si += Ar[j]*yj.y + Ai[j]*yj.x;
  }
  c32 yr = sh.rec.yts[fi][r];
  float qd = (yr.x*sr + yr.y*si) * w;
  float lw = r0 ? ld * w : 0.0f;

  #pragma unroll
  for (int d = 1; d < 64; d <<= 1) {
    lw += __shfl_xor(lw, d, 64);
    qd += __shfl_xor(qd, d, 64);
  }
  if ((t & 63) == 0) { redl[t >> 6] = lw; redq[t >> 6] = qd; }
  __syncthreads();   // all recursion LDS reads complete before plane reuse
  if (t == 0) {
    atomicAdd(out + OUT_LD, redl[0] + redl[1] + redl[2] + redl[3]);
    atomicAdd(out + OUT_QD, redq[0] + redq[1] + redq[2] + redq[3]);
  }

  // ---- coalesced store via LDS staging ----
  const int lf = t & 15;            // frequency offset within block
  const int cl = t >> 4;            // row cluster
  const int fL = f0 + lf;
  const bool dir_ok = (fL <= NHALF);
  const bool mir_ok = (fL > 0 && fL < NHALF);
  const size_t fD = (size_t)fL;
  const size_t fM = (size_t)(NF - fL);

  // RE plane
  {
    float4* prow = (float4*)&sh.plane[fi][r * 16];   // 16B-aligned (row stride 1040B)
    prow[0] = make_float4(Ar[0],  Ar[1],  Ar[2],  Ar[3]);
    prow[1] = make_float4(Ar[4],  Ar[5],  Ar[6],  Ar[7]);
    prow[2] = make_float4(Ar[8],  Ar[9],  Ar[10], Ar[11]);
    prow[3] = make_float4(Ar[12], Ar[13], Ar[14], Ar[15]);
  }
  __syncthreads();
  #pragma unroll
  for (int u = 0; u < 16; ++u) {
    int rr = u * 16 + cl;
    float v = sh.plane[lf][rr];
    size_t o = (size_t)rr * NF;
    if (dir_ok) out[o + fD] = v;
    if (mir_ok) out[o + fM] = v;
  }
  __syncthreads();
  // IM plane
  {
    float4* prow = (float4*)&sh.plane[fi][r * 16];
    prow[0] = make_float4(Ai[0],  Ai[1],  Ai[2],  Ai[3]);
    prow[1] = make_float4(Ai[4],  Ai[5],  Ai[6],  Ai[7]);
    prow[2] = make_float4(Ai[8],  Ai[9],  Ai[10], Ai[11]);
    prow[3] = make_float4(Ai[12], Ai[13], Ai[14], Ai[15]);
  }
  __syncthreads();
  #pragma unroll
  for (int u = 0; u < 16; ++u) {
    int rr = u * 16 + cl;
    float v = sh.plane[lf][rr];
    size_t o = AIMAG + (size_t)rr * NF;
    if (dir_ok) out[o + fD] = v;
    if (mir_ok) out[o + fM] = -v;
  }
}

extern "C" void kernel_launch(void* const* d_in, const int* in_sizes, int n_in,
                              void* d_out, int out_size, void* d_ws, size_t ws_size,
                              hipStream_t stream) {
  const float* k1 = (const float*)d_in[0];
  const float* y  = (const float*)d_in[1];
  float* out = (float*)d_out;
  c32* scratch = (c32*)d_out;   // 79.7 MB < 134 MB out buffer, overwritten later
  c32* spec    = (c32*)d_ws;    // 76 MiB workspace

  dim3 grid(16, NROWS);
  dim3 blk(256);

  fft_pass1                <<<grid, blk, 0, stream>>>(k1, y, scratch);
  fft_pass<4096, 16, false><<<grid, blk, 0, stream>>>(scratch, spec);
  fft_pass<256, 256, false><<<grid, blk, 0, stream>>>(spec, scratch);
  fft_pass<16, 4096, true> <<<grid, blk, 0, stream>>>(scratch, spec);

  init_out<<<1, 64, 0, stream>>>(out);
  invert_write<<<2049, blk, 0, stream>>>(spec, out);   // f = 0..32768
}